// Round 1
// 973.783 us; speedup vs baseline: 1.1761x; 1.1761x over previous
//
#include <hip/hip_runtime.h>
#include <hip/hip_bf16.h>

// ---------------------------------------------------------------------------
// AttentionHeteroConv. R8 = R7 restructured for occupancy + critical path:
//  (1) ATN 8->4: LDS 72.7KB -> ~35.4KB, __launch_bounds__(256,4) -> 4 blk/CU
//      (16 waves/CU vs 8). Gather = 1 node/wave (half the serial chain).
//  (2) Wip pre-converted ONCE to bf16 MFMA-image [ks][384][32] in workspace;
//      attn waves read B fragments directly from L2 (coalesced 1KB/wave) --
//      removes per-block B LDS staging, 8 barriers/block, ~800 f2bf VALU
//      instrs/thread, and the B-tile bank conflicts.
//  (3) mean row folded into MFMA C-write (acc*cinv+bias) -- P3 deleted.
//  (4) attention processes 2 heads per pass: 6 barriers instead of 12.
// Transform / CSR / outproj unchanged (R3-proven).
// ---------------------------------------------------------------------------

#define C 128
#define NHEAD 4
#define DH 32
#define QK_SCALE 0.17677669529663687f  // 1/sqrt(32)

typedef __attribute__((ext_vector_type(8))) short bf16x8;
typedef __attribute__((ext_vector_type(4))) short short4v;
typedef __attribute__((ext_vector_type(2))) short short2v;
typedef __attribute__((ext_vector_type(4))) float f32x4;

__device__ __forceinline__ short f2bf(float f) {
    unsigned u = __float_as_uint(f);
    unsigned r = u + 0x7FFFu + ((u >> 16) & 1u);   // round-to-nearest-even
    return (short)(r >> 16);
}

// ---------------------------------------------------------------------------
// K2: transform: h = x@Wnb^T + bnb ; self = x@Wself^T + bself  (R3 version)
// ---------------------------------------------------------------------------
__global__ __launch_bounds__(256) void transform_kernel(
    const float* __restrict__ x, int n_rows,
    const float* __restrict__ Wnb, const float* __restrict__ bnb,
    const float* __restrict__ Wself, const float* __restrict__ bself,
    float* __restrict__ h, float* __restrict__ selfout)
{
    __shared__ float At[32][C];
    const int tid = threadIdx.x;
    const int row0 = blockIdx.x * 32;

    for (int i = tid; i < 32 * 32; i += 256) {
        int r = i >> 5, c4 = i & 31;
        float4 v = make_float4(0.f, 0.f, 0.f, 0.f);
        if (row0 + r < n_rows) v = ((const float4*)x)[(size_t)(row0 + r) * 32 + c4];
        ((float4*)At[r])[c4] = v;
    }
    __syncthreads();

    const int col = tid & 127;
    const float* W = (tid < 128) ? Wnb : Wself;
    const float* bb = (tid < 128) ? bnb : bself;
    float* outp = (tid < 128) ? h : selfout;

    float acc[32];
#pragma unroll
    for (int r = 0; r < 32; r++) acc[r] = 0.f;

    const float4* w4 = (const float4*)(W + (size_t)col * C);
    for (int k4 = 0; k4 < 32; k4 += 4) {
        float4 w0 = w4[k4], w1 = w4[k4 + 1], w2 = w4[k4 + 2], w3 = w4[k4 + 3];
#pragma unroll
        for (int r = 0; r < 32; r++) {
            const float4* a4 = (const float4*)At[r];
            float4 a0 = a4[k4], a1 = a4[k4 + 1], a2 = a4[k4 + 2], a3 = a4[k4 + 3];
            acc[r] += a0.x * w0.x + a0.y * w0.y + a0.z * w0.z + a0.w * w0.w
                    + a1.x * w1.x + a1.y * w1.y + a1.z * w1.z + a1.w * w1.w
                    + a2.x * w2.x + a2.y * w2.y + a2.z * w2.z + a2.w * w2.w
                    + a3.x * w3.x + a3.y * w3.y + a3.z * w3.z + a3.w * w3.w;
        }
    }
    const float bias = bb[col];
#pragma unroll
    for (int r = 0; r < 32; r++) {
        int row = row0 + r;
        if (row < n_rows) outp[(size_t)row * C + col] = acc[r] + bias;
    }
}

// ---------------------------------------------------------------------------
// CSR build: zero + histogram + exclusive-scan (single block) + fill.
// ---------------------------------------------------------------------------
__global__ __launch_bounds__(256) void zero_kernel(int* __restrict__ p, int n)
{
    int i = blockIdx.x * 256 + threadIdx.x;
    if (i < n) p[i] = 0;
}

__global__ __launch_bounds__(256) void hist_kernel(
    const int* __restrict__ dst, int n, int* __restrict__ cur)
{
    int i = blockIdx.x * 256 + threadIdx.x;
    if (i < n) atomicAdd(&cur[dst[i]], 1);
}

__global__ __launch_bounds__(1024) void scan_kernel(int* __restrict__ cur, int n)
{
    __shared__ int wsum[16];
    __shared__ int carryS;
    const int tid = threadIdx.x, lane = tid & 63, wv = tid >> 6;
    if (tid == 0) carryS = 0;
    __syncthreads();
    for (int base = 0; base < n; base += 1024) {
        int i = base + tid;
        int v = (i < n) ? cur[i] : 0;
        int x = v;
#pragma unroll
        for (int d = 1; d < 64; d <<= 1) {
            int t = __shfl_up(x, d, 64);
            if (lane >= d) x += t;
        }
        if (lane == 63) wsum[wv] = x;
        int carry = carryS;
        __syncthreads();
        int wpre = 0;
#pragma unroll
        for (int w2 = 0; w2 < 16; w2++) wpre += (w2 < wv) ? wsum[w2] : 0;
        int excl = x - v + wpre + carry;
        if (i < n) cur[i] = excl;
        __syncthreads();
        if (tid == 0) {
            int t = 0;
#pragma unroll
            for (int w2 = 0; w2 < 16; w2++) t += wsum[w2];
            carryS = carry + t;
        }
        __syncthreads();
    }
}

__global__ __launch_bounds__(256) void fill_kernel(
    const int* __restrict__ src, const int* __restrict__ dst, int n,
    int* __restrict__ cur, int* __restrict__ csr)
{
    int i = blockIdx.x * 256 + threadIdx.x;
    if (i < n) {
        int p = atomicAdd(&cur[dst[i]], 1);
        csr[p] = src[i];
    }
}

// ---------------------------------------------------------------------------
// K3b: Wip fp32 [384][128] -> bf16 MFMA image [ks][384][32] (dense, 98304 B).
// Element (ks,n,k) at byte ks*24576 + n*64 + k*2, k in [0,32).
// ---------------------------------------------------------------------------
__global__ __launch_bounds__(256) void wip2bf_kernel(
    const float* __restrict__ Wip, unsigned* __restrict__ img)
{
    int id = blockIdx.x * 256 + threadIdx.x;     // 4*384*16 = 24576 pair-slots
    if (id >= 4 * 384 * 16) return;
    int ks = id / (384 * 16);
    int rem = id - ks * (384 * 16);
    int n = rem >> 4, kk = rem & 15;             // kk = pair index (2 bf16)
    float a = Wip[(size_t)n * C + ks * 32 + kk * 2 + 0];
    float b = Wip[(size_t)n * C + ks * 32 + kk * 2 + 1];
    unsigned pa = ((unsigned)(unsigned short)f2bf(a))
                | (((unsigned)(unsigned short)f2bf(b)) << 16);
    img[(size_t)ks * 6144 + n * 16 + kk] = pa;
}

// ---------------------------------------------------------------------------
// K4: fused gather-aggregate + bf16-MFMA qkv GEMM + attention, 4 nodes/block.
// LDS: R overlay (floats): A bf16 tile [16][136] (bytes 0..4351) -> qkv fp32
// [20][388] after GEMM. B fragments read directly from global bf16 image.
// MFMA 16x16x32: M=16 (4 nodes x 4 srcs), N=384 split 4 waves x 96 cols,
// 6 N-tiles x 4 K-steps = 24 MFMA/wave, acc 6 x f32x4.
// ---------------------------------------------------------------------------
#define ATN 4
#define QROW 388
#define RSZ (20 * QROW)   // 7760 floats = 31040 B

__global__ __launch_bounds__(256, 4) void attn_fused_kernel(
    const float* __restrict__ h_src, const int* __restrict__ csr,
    const int* __restrict__ cur, const float* __restrict__ selfF,
    const short* __restrict__ wipbf, const float* __restrict__ bip,
    float* __restrict__ omean_g, int n_nodes)
{
    __shared__ float R[RSZ];
    __shared__ float omean[ATN][C];
    __shared__ float att[2][ATN][5][5];
    __shared__ float bipS[384];
    __shared__ float cinv[ATN];

    const int tid = threadIdx.x;
    const int lane = tid & 63;
    const int wv = tid >> 6;
    const int node0 = blockIdx.x * ATN;

    char* Abase = (char*)R;            // bf16 A tile [16][136], stride 272 B

    // ---- P0a: stage bip + self rows (A row node*4+0, bf16) ----
    for (int i = tid; i < 384; i += 256) bipS[i] = bip[i];
    if (tid < 128) {
        int r = tid >> 5, c4 = tid & 31;
        int node = node0 + r;
        float4 v = make_float4(0.f, 0.f, 0.f, 0.f);
        if (node < n_nodes) v = ((const float4*)selfF)[(size_t)node * 32 + c4];
        short4v b;
        b.x = f2bf(v.x); b.y = f2bf(v.y); b.z = f2bf(v.z); b.w = f2bf(v.w);
        *(short4v*)(Abase + (r * 4) * 272 + c4 * 8) = b;
    }

    // ---- P0b: gather max/min/sum -> A rows wv*4+{1,2,3} (one node/wave) ----
    {
        const float2* h2 = (const float2*)h_src;
        int node = node0 + wv;
        float2 vs = make_float2(0.f, 0.f);
        float2 vmx = make_float2(-3.4e38f, -3.4e38f);
        float2 vmn = make_float2(3.4e38f, 3.4e38f);
        int deg = 0;
        if (node < n_nodes) {
            int start = (node == 0) ? 0 : cur[node - 1];
            int end = cur[node];
            deg = end - start;
            int e = start;
            for (; e + 4 <= end; e += 4) {
                int s0 = csr[e], s1 = csr[e + 1], s2 = csr[e + 2], s3 = csr[e + 3];
                float2 v0 = h2[(size_t)s0 * 64 + lane];
                float2 v1 = h2[(size_t)s1 * 64 + lane];
                float2 v2 = h2[(size_t)s2 * 64 + lane];
                float2 v3 = h2[(size_t)s3 * 64 + lane];
                vs.x += v0.x + v1.x + v2.x + v3.x;
                vs.y += v0.y + v1.y + v2.y + v3.y;
                vmx.x = fmaxf(fmaxf(vmx.x, v0.x), fmaxf(v1.x, fmaxf(v2.x, v3.x)));
                vmx.y = fmaxf(fmaxf(vmx.y, v0.y), fmaxf(v1.y, fmaxf(v2.y, v3.y)));
                vmn.x = fminf(fminf(vmn.x, v0.x), fminf(v1.x, fminf(v2.x, v3.x)));
                vmn.y = fminf(fminf(vmn.y, v0.y), fminf(v1.y, fminf(v2.y, v3.y)));
            }
            for (; e < end; e++) {
                int s0 = csr[e];
                float2 v0 = h2[(size_t)s0 * 64 + lane];
                vs.x += v0.x; vs.y += v0.y;
                vmx.x = fmaxf(vmx.x, v0.x); vmx.y = fmaxf(vmx.y, v0.y);
                vmn.x = fminf(vmn.x, v0.x); vmn.y = fminf(vmn.y, v0.y);
            }
        }
        if (deg == 0) {
            vmx = make_float2(0.f, 0.f);
            vmn = make_float2(0.f, 0.f);
        }
        short2v p;
        p.x = f2bf(vmx.x); p.y = f2bf(vmx.y);
        *(short2v*)(Abase + (wv * 4 + 1) * 272 + lane * 4) = p;
        p.x = f2bf(vmn.x); p.y = f2bf(vmn.y);
        *(short2v*)(Abase + (wv * 4 + 2) * 272 + lane * 4) = p;
        p.x = f2bf(vs.x); p.y = f2bf(vs.y);
        *(short2v*)(Abase + (wv * 4 + 3) * 272 + lane * 4) = p;
        if (lane == 0) cinv[wv] = 1.f / (float)max(deg, 1);
    }
    __syncthreads();   // A tile + cinv visible

    // ---- P1: MFMA GEMM qkv = A @ Wip^T  (M=16, N=384, K=128) ----
    // B fragments straight from L2-resident bf16 image (1KB/wave coalesced).
    const int quad = lane >> 4;
    const int col16 = lane & 15;

    f32x4 acc[6];
#pragma unroll
    for (int t = 0; t < 6; t++) acc[t] = (f32x4){0.f, 0.f, 0.f, 0.f};

    const char* Bg = (const char*)wipbf + (size_t)(wv * 96 + col16) * 64 + quad * 16;
#pragma unroll
    for (int ks = 0; ks < 4; ks++) {
        bf16x8 af = *(const bf16x8*)(Abase + col16 * 272 + ks * 64 + quad * 16);
#pragma unroll
        for (int t = 0; t < 6; t++) {
            bf16x8 bfr = *(const bf16x8*)(Bg + ks * 24576 + t * 1024);
            acc[t] = __builtin_amdgcn_mfma_f32_16x16x32_bf16(af, bfr, acc[t], 0, 0, 0);
        }
    }
    __syncthreads();   // all waves done reading A region

    // ---- P2: C-frags (+bias) -> qkv overlay rows node*5+s; mean row folded
    //      in from the sum accumulator: mean = acc_sum*cinv + bias. ----
    {
        const float ci = cinv[quad];   // node == quad
#pragma unroll
        for (int t = 0; t < 6; t++) {
            int col = wv * 96 + t * 16 + col16;
            float bias = bipS[col];
#pragma unroll
            for (int reg = 0; reg < 4; reg++) {   // node=quad, s=reg
                R[(quad * 5 + reg) * QROW + col] = acc[t][reg] + bias;
            }
            R[(quad * 5 + 4) * QROW + col] = acc[t][3] * ci + bias;
        }
    }
    __syncthreads();

    // ---- P4: scores/softmax/PV, 2 heads per pass ----
#pragma unroll
    for (int hp = 0; hp < 2; hp++) {
        if (tid < 200) {
            int sub = (tid >= 100) ? 1 : 0;
            int rem = tid - sub * 100;
            int n = rem / 25, ij = rem - n * 25, i = ij / 5, j = ij - (ij / 5) * 5;
            int h = hp * 2 + sub;
            const float4* qr = (const float4*)&R[(n * 5 + i) * QROW + h * DH];
            const float4* kr = (const float4*)&R[(n * 5 + j) * QROW + C + h * DH];
            float s = 0.f;
#pragma unroll
            for (int d4 = 0; d4 < 8; d4++) {
                float4 q = qr[d4], k = kr[d4];
                s += q.x * k.x + q.y * k.y + q.z * k.z + q.w * k.w;
            }
            att[sub][n][i][j] = s * QK_SCALE;
        }
        __syncthreads();
        if (tid < 40) {
            int sub = (tid >= 20) ? 1 : 0;
            int rem = tid - sub * 20;
            int n = rem / 5, i = rem - (rem / 5) * 5;
            float m = att[sub][n][i][0];
#pragma unroll
            for (int j = 1; j < 5; j++) m = fmaxf(m, att[sub][n][i][j]);
            float e[5], l = 0.f;
#pragma unroll
            for (int j = 0; j < 5; j++) { e[j] = __expf(att[sub][n][i][j] - m); l += e[j]; }
            float inv = 0.2f / l;   // fold mean over 5 tokens
#pragma unroll
            for (int j = 0; j < 5; j++) att[sub][n][i][j] = e[j] * inv;
        }
        __syncthreads();
        {
            int sub = tid >> 7, rem = tid & 127, n = rem >> 5, d = rem & 31;
            int h = hp * 2 + sub;
            float a2 = 0.f;
#pragma unroll
            for (int j = 0; j < 5; j++) {
                float wj = att[sub][n][0][j] + att[sub][n][1][j] + att[sub][n][2][j]
                         + att[sub][n][3][j] + att[sub][n][4][j];
                a2 += wj * R[(n * 5 + j) * QROW + 2 * C + h * DH + d];
            }
            omean[n][h * DH + d] = a2;
        }
        __syncthreads();
    }

    // ---- P5: omean -> global ----
#pragma unroll
    for (int i = 0; i < 2; i++) {
        int id = tid + i * 256;
        int n = id >> 7, c = id & 127;
        int node = node0 + n;
        if (node < n_nodes) omean_g[(size_t)node * C + c] = omean[n][c];
    }
}

// ---------------------------------------------------------------------------
// K5: out = self(d_out) + omean @ Wop^T + bop.  (R3 version)
// ---------------------------------------------------------------------------
__global__ __launch_bounds__(256, 4) void outproj_kernel(
    const float* __restrict__ omean_g, const float* __restrict__ Wop,
    const float* __restrict__ bop, float* __restrict__ out, int M)
{
    __shared__ float As[32 * 132];
    __shared__ float Bs[32 * 132];
    __shared__ float bopS[C];
    const int tid = threadIdx.x;
    const int m0 = blockIdx.x * 32;

    if (tid < C) bopS[tid] = bop[tid];
#pragma unroll
    for (int i = 0; i < 4; i++) {
        int id = tid + i * 256;
        int r = id >> 5, c4 = id & 31;
        float4 v = make_float4(0.f, 0.f, 0.f, 0.f);
        int m = m0 + r;
        if (m < M) v = ((const float4*)omean_g)[(size_t)m * 32 + c4];
        *(float4*)&As[r * 132 + c4 * 4] = v;
    }

    const int tn = tid & 31;
    const int tm = tid >> 5;
    float acc[4][4];
#pragma unroll
    for (int m = 0; m < 4; m++)
#pragma unroll
        for (int n = 0; n < 4; n++) acc[m][n] = 0.f;

    for (int ks = 0; ks < 4; ks++) {
        __syncthreads();
        for (int i = 0; i < 4; i++) {
            int id = tid + i * 256;          // 1024 = 128 n x 8 q
            int n = id >> 3, q = id & 7;
            float4 w = ((const float4*)Wop)[(size_t)n * 32 + ks * 8 + q];
            Bs[(q * 4 + 0) * 132 + n] = w.x;
            Bs[(q * 4 + 1) * 132 + n] = w.y;
            Bs[(q * 4 + 2) * 132 + n] = w.z;
            Bs[(q * 4 + 3) * 132 + n] = w.w;
        }
        __syncthreads();
#pragma unroll 4
        for (int k4 = 0; k4 < 8; k4++) {
            float4 a[4];
#pragma unroll
            for (int m = 0; m < 4; m++)
                a[m] = *(const float4*)&As[(tm * 4 + m) * 132 + ks * 32 + k4 * 4];
#pragma unroll
            for (int kk = 0; kk < 4; kk++) {
                float4 b = *(const float4*)&Bs[(k4 * 4 + kk) * 132 + tn * 4];
#pragma unroll
                for (int m = 0; m < 4; m++) {
                    float av = ((const float*)&a[m])[kk];
                    acc[m][0] += av * b.x; acc[m][1] += av * b.y;
                    acc[m][2] += av * b.z; acc[m][3] += av * b.w;
                }
            }
        }
    }

#pragma unroll
    for (int m = 0; m < 4; m++) {
        int row = m0 + tm * 4 + m;
        if (row < M) {
            float4* o = (float4*)&out[(size_t)row * C + tn * 4];
            float4 r = *o;
            r.x += acc[m][0] + bopS[tn * 4 + 0];
            r.y += acc[m][1] + bopS[tn * 4 + 1];
            r.z += acc[m][2] + bopS[tn * 4 + 2];
            r.w += acc[m][3] + bopS[tn * 4 + 3];
            *o = r;
        }
    }
}

// ---------------------------------------------------------------------------
extern "C" void kernel_launch(void* const* d_in, const int* in_sizes, int n_in,
                              void* d_out, int out_size, void* d_ws, size_t ws_size,
                              hipStream_t stream) {
    const float* x_user = (const float*)d_in[0];
    const float* x_item = (const float*)d_in[1];
    const int*   ei_u2i = (const int*)d_in[2];
    const int*   ei_i2u = (const int*)d_in[3];
    const float* W_nb   = (const float*)d_in[4];
    const float* b_nb   = (const float*)d_in[5];
    const float* W_self = (const float*)d_in[6];
    const float* b_self = (const float*)d_in[7];
    const float* Wip    = (const float*)d_in[8];
    const float* bip    = (const float*)d_in[9];
    const float* Wop    = (const float*)d_in[10];
    const float* bop    = (const float*)d_in[11];

    const int NU = in_sizes[0] / C;
    const int NI = in_sizes[1] / C;
    const int E1 = in_sizes[2] / 2;
    const int E2 = in_sizes[3] / 2;

    float* out_user = (float*)d_out;
    float* out_item = out_user + (size_t)NU * C;

    // workspace: wipbf (24576 floats = 98304 B) | h (rc) | omean (rc)
    //          | cur (maxN ints) | csr (maxE ints)
    float* ws = (float*)d_ws;
    short* wipbf     = (short*)ws;
    float* h_all     = ws + 24576;
    const size_t rc = (size_t)(NU + NI) * C;
    float* omean_all = h_all + rc;
    int*   cur       = (int*)(omean_all + rc);
    const int maxN   = (NU > NI) ? NU : NI;
    int*   csr       = cur + maxN;

    float* h_user = h_all;
    float* h_item = h_all + (size_t)NU * C;
    float* om_user = omean_all;
    float* om_item = omean_all + (size_t)NU * C;

    wip2bf_kernel<<<96, 256, 0, stream>>>(Wip, (unsigned*)wipbf);

    transform_kernel<<<(NU + 31) / 32, 256, 0, stream>>>(
        x_user, NU, W_nb, b_nb, W_self, b_self, h_user, out_user);
    transform_kernel<<<(NI + 31) / 32, 256, 0, stream>>>(
        x_item, NI, W_nb, b_nb, W_self, b_self, h_item, out_item);

    // direction A: user -> item
    zero_kernel<<<(NI + 255) / 256, 256, 0, stream>>>(cur, NI);
    hist_kernel<<<(E1 + 255) / 256, 256, 0, stream>>>(ei_u2i + E1, E1, cur);
    scan_kernel<<<1, 1024, 0, stream>>>(cur, NI);
    fill_kernel<<<(E1 + 255) / 256, 256, 0, stream>>>(ei_u2i, ei_u2i + E1, E1, cur, csr);
    attn_fused_kernel<<<(NI + ATN - 1) / ATN, 256, 0, stream>>>(
        h_user, csr, cur, out_item, wipbf, bip, om_item, NI);

    // direction B: item -> user
    zero_kernel<<<(NU + 255) / 256, 256, 0, stream>>>(cur, NU);
    hist_kernel<<<(E2 + 255) / 256, 256, 0, stream>>>(ei_i2u + E2, E2, cur);
    scan_kernel<<<1, 1024, 0, stream>>>(cur, NU);
    fill_kernel<<<(E2 + 255) / 256, 256, 0, stream>>>(ei_i2u, ei_i2u + E2, E2, cur, csr);
    attn_fused_kernel<<<(NU + ATN - 1) / ATN, 256, 0, stream>>>(
        h_item, csr, cur, out_user, wipbf, bip, om_user, NU);

    outproj_kernel<<<(NU + NI + 31) / 32, 256, 0, stream>>>(
        omean_all, Wop, bop, (float*)d_out, NU + NI);
}

// Round 2
// 819.768 us; speedup vs baseline: 1.3971x; 1.1879x over previous
//
#include <hip/hip_runtime.h>
#include <hip/hip_bf16.h>

// ---------------------------------------------------------------------------
// AttentionHeteroConv. R9 = R8 with:
//  (1) transform rewritten: 64-row blocks, 8x8 register tiles, strided column
//      ownership (col = tn + 32j) so B is staged row-major [n][36] with
//      conflict-free b128 reads. LDS traffic /4 (1 -> 4 FMA per LDS float).
//  (2) outproj same structure (8x4 tiles, 64-row blocks).
//  (3) attn: LDS 35.8KB -> 31.9KB (omean/bipS buffers dropped; PV writes
//      direct to global; bias from L2) -> 5 blocks/CU; gather 8-wide with
//      masked full-width tail (ceil(deg/8) latency rounds).
// ---------------------------------------------------------------------------

#define C 128
#define NHEAD 4
#define DH 32
#define QK_SCALE 0.17677669529663687f  // 1/sqrt(32)

typedef __attribute__((ext_vector_type(8))) short bf16x8;
typedef __attribute__((ext_vector_type(4))) short short4v;
typedef __attribute__((ext_vector_type(2))) short short2v;
typedef __attribute__((ext_vector_type(4))) float f32x4;

__device__ __forceinline__ short f2bf(float f) {
    unsigned u = __float_as_uint(f);
    unsigned r = u + 0x7FFFu + ((u >> 16) & 1u);   // round-to-nearest-even
    return (short)(r >> 16);
}

// ---------------------------------------------------------------------------
// K2: transform: h = x@Wnb^T + bnb ; self = x@Wself^T + bself.
// 64 rows/block, 256 outcols (Wnb|Wself). Thread (tm,tn): rows tm*8..+7,
// cols tn+32j (j=0..7). A [64][132] LDS, B chunk [256][36] LDS per ks.
// Per k4: 8 a-b128 + 8 b-b128 for 256 FMA (4 FMA/float).
// ---------------------------------------------------------------------------
__global__ __launch_bounds__(256, 2) void transform_kernel(
    const float* __restrict__ x, int n_rows,
    const float* __restrict__ Wnb, const float* __restrict__ bnb,
    const float* __restrict__ Wself, const float* __restrict__ bself,
    float* __restrict__ h, float* __restrict__ selfout)
{
    __shared__ float As[64 * 132];   // 33792 B
    __shared__ float Bs[256 * 36];   // 36864 B
    __shared__ float biasS[256];

    const int tid = threadIdx.x;
    const int row0 = blockIdx.x * 64;

    biasS[tid] = (tid < 128) ? bnb[tid] : bself[tid - 128];

    // stage A: 64 rows x 32 float4
#pragma unroll
    for (int i = 0; i < 8; i++) {
        int id = tid + i * 256;
        int r = id >> 5, c4 = id & 31;
        float4 v = make_float4(0.f, 0.f, 0.f, 0.f);
        if (row0 + r < n_rows) v = ((const float4*)x)[(size_t)(row0 + r) * 32 + c4];
        *(float4*)&As[r * 132 + c4 * 4] = v;
    }

    const int tm = tid >> 5;   // 0..7
    const int tn = tid & 31;   // 0..31

    float acc[8][8];
#pragma unroll
    for (int m = 0; m < 8; m++)
#pragma unroll
        for (int j = 0; j < 8; j++) acc[m][j] = 0.f;

    for (int ks = 0; ks < 4; ks++) {
        __syncthreads();
        // stage B chunk: rows n of [Wnb;Wself], cols ks*32..+31
#pragma unroll
        for (int i = 0; i < 8; i++) {
            int id = tid + i * 256;          // 2048 = 256 n x 8 q
            int n = id >> 3, q = id & 7;
            const float4* src = (n < 128)
                ? &((const float4*)Wnb)[(size_t)n * 32 + ks * 8 + q]
                : &((const float4*)Wself)[(size_t)(n - 128) * 32 + ks * 8 + q];
            *(float4*)&Bs[n * 36 + q * 4] = *src;
        }
        __syncthreads();

        for (int k4 = 0; k4 < 8; k4++) {
            float4 a[8];
#pragma unroll
            for (int m = 0; m < 8; m++)
                a[m] = *(const float4*)&As[(tm * 8 + m) * 132 + ks * 32 + k4 * 4];
            float4 b[8];
#pragma unroll
            for (int j = 0; j < 8; j++)
                b[j] = *(const float4*)&Bs[(tn + 32 * j) * 36 + k4 * 4];
#pragma unroll
            for (int m = 0; m < 8; m++) {
                float4 av = a[m];
#pragma unroll
                for (int j = 0; j < 8; j++) {
                    float4 bv = b[j];
                    acc[m][j] += av.x * bv.x + av.y * bv.y
                               + av.z * bv.z + av.w * bv.w;
                }
            }
        }
    }

#pragma unroll
    for (int m = 0; m < 8; m++) {
        int row = row0 + tm * 8 + m;
        if (row < n_rows) {
#pragma unroll
            for (int j = 0; j < 8; j++) {
                int jj = tn + 32 * j;
                float v = acc[m][j] + biasS[jj];
                if (j < 4) h[(size_t)row * C + jj] = v;
                else       selfout[(size_t)row * C + (jj - 128)] = v;
            }
        }
    }
}

// ---------------------------------------------------------------------------
// CSR build: zero + histogram + exclusive-scan (single block) + fill.
// ---------------------------------------------------------------------------
__global__ __launch_bounds__(256) void zero_kernel(int* __restrict__ p, int n)
{
    int i = blockIdx.x * 256 + threadIdx.x;
    if (i < n) p[i] = 0;
}

__global__ __launch_bounds__(256) void hist_kernel(
    const int* __restrict__ dst, int n, int* __restrict__ cur)
{
    int i = blockIdx.x * 256 + threadIdx.x;
    if (i < n) atomicAdd(&cur[dst[i]], 1);
}

__global__ __launch_bounds__(1024) void scan_kernel(int* __restrict__ cur, int n)
{
    __shared__ int wsum[16];
    __shared__ int carryS;
    const int tid = threadIdx.x, lane = tid & 63, wv = tid >> 6;
    if (tid == 0) carryS = 0;
    __syncthreads();
    for (int base = 0; base < n; base += 1024) {
        int i = base + tid;
        int v = (i < n) ? cur[i] : 0;
        int x = v;
#pragma unroll
        for (int d = 1; d < 64; d <<= 1) {
            int t = __shfl_up(x, d, 64);
            if (lane >= d) x += t;
        }
        if (lane == 63) wsum[wv] = x;
        int carry = carryS;
        __syncthreads();
        int wpre = 0;
#pragma unroll
        for (int w2 = 0; w2 < 16; w2++) wpre += (w2 < wv) ? wsum[w2] : 0;
        int excl = x - v + wpre + carry;
        if (i < n) cur[i] = excl;
        __syncthreads();
        if (tid == 0) {
            int t = 0;
#pragma unroll
            for (int w2 = 0; w2 < 16; w2++) t += wsum[w2];
            carryS = carry + t;
        }
        __syncthreads();
    }
}

__global__ __launch_bounds__(256) void fill_kernel(
    const int* __restrict__ src, const int* __restrict__ dst, int n,
    int* __restrict__ cur, int* __restrict__ csr)
{
    int i = blockIdx.x * 256 + threadIdx.x;
    if (i < n) {
        int p = atomicAdd(&cur[dst[i]], 1);
        csr[p] = src[i];
    }
}

// ---------------------------------------------------------------------------
// K3b: Wip fp32 [384][128] -> bf16 MFMA image [ks][384][32] (dense, 98304 B).
// ---------------------------------------------------------------------------
__global__ __launch_bounds__(256) void wip2bf_kernel(
    const float* __restrict__ Wip, unsigned* __restrict__ img)
{
    int id = blockIdx.x * 256 + threadIdx.x;     // 4*384*16 = 24576 pair-slots
    if (id >= 4 * 384 * 16) return;
    int ks = id / (384 * 16);
    int rem = id - ks * (384 * 16);
    int n = rem >> 4, kk = rem & 15;             // kk = pair index (2 bf16)
    float a = Wip[(size_t)n * C + ks * 32 + kk * 2 + 0];
    float b = Wip[(size_t)n * C + ks * 32 + kk * 2 + 1];
    unsigned pa = ((unsigned)(unsigned short)f2bf(a))
                | (((unsigned)(unsigned short)f2bf(b)) << 16);
    img[(size_t)ks * 6144 + n * 16 + kk] = pa;
}

// ---------------------------------------------------------------------------
// K4: fused gather-aggregate + bf16-MFMA qkv GEMM + attention, 4 nodes/block.
// LDS 31856 B -> 5 blocks/CU. Gather 8-wide with masked tail. PV writes
// straight to global; bias read from L2-resident bip.
// ---------------------------------------------------------------------------
#define ATN 4
#define QROW 388
#define RSZ (20 * QROW)   // 7760 floats = 31040 B

__global__ __launch_bounds__(256, 5) void attn_fused_kernel(
    const float* __restrict__ h_src, const int* __restrict__ csr,
    const int* __restrict__ cur, const float* __restrict__ selfF,
    const short* __restrict__ wipbf, const float* __restrict__ bip,
    float* __restrict__ omean_g, int n_nodes)
{
    __shared__ float R[RSZ];
    __shared__ float att[2][ATN][5][5];
    __shared__ float cinv[ATN];

    const int tid = threadIdx.x;
    const int lane = tid & 63;
    const int wv = tid >> 6;
    const int node0 = blockIdx.x * ATN;

    char* Abase = (char*)R;            // bf16 A tile [16][136], stride 272 B

    // ---- P0a: self rows (A row node*4+0, bf16) ----
    if (tid < 128) {
        int r = tid >> 5, c4 = tid & 31;
        int node = node0 + r;
        float4 v = make_float4(0.f, 0.f, 0.f, 0.f);
        if (node < n_nodes) v = ((const float4*)selfF)[(size_t)node * 32 + c4];
        short4v b;
        b.x = f2bf(v.x); b.y = f2bf(v.y); b.z = f2bf(v.z); b.w = f2bf(v.w);
        *(short4v*)(Abase + (r * 4) * 272 + c4 * 8) = b;
    }

    // ---- P0b: gather max/min/sum -> A rows wv*4+{1,2,3} (one node/wave) ----
    {
        const float2* h2 = (const float2*)h_src;
        int node = node0 + wv;
        float2 vs = make_float2(0.f, 0.f);
        float2 vmx = make_float2(-3.4e38f, -3.4e38f);
        float2 vmn = make_float2(3.4e38f, 3.4e38f);
        int deg = 0;
        if (node < n_nodes) {
            int start = (node == 0) ? 0 : cur[node - 1];
            int end = cur[node];
            deg = end - start;
            int e = start;
            for (; e + 8 <= end; e += 8) {
                float2 v[8];
#pragma unroll
                for (int i = 0; i < 8; i++) {
                    int s = csr[e + i];
                    v[i] = h2[(size_t)s * 64 + lane];
                }
#pragma unroll
                for (int i = 0; i < 8; i++) {
                    vs.x += v[i].x; vs.y += v[i].y;
                    vmx.x = fmaxf(vmx.x, v[i].x); vmx.y = fmaxf(vmx.y, v[i].y);
                    vmn.x = fminf(vmn.x, v[i].x); vmn.y = fminf(vmn.y, v[i].y);
                }
            }
            if (e < end) {   // masked full-width tail: one latency round
                int last = end - 1;
                float2 v[8];
#pragma unroll
                for (int i = 0; i < 8; i++) {
                    int idx = e + i;
                    int s = csr[(idx <= last) ? idx : last];
                    v[i] = h2[(size_t)s * 64 + lane];
                }
#pragma unroll
                for (int i = 0; i < 8; i++) {
                    if (e + i <= last) {   // wave-uniform
                        vs.x += v[i].x; vs.y += v[i].y;
                        vmx.x = fmaxf(vmx.x, v[i].x); vmx.y = fmaxf(vmx.y, v[i].y);
                        vmn.x = fminf(vmn.x, v[i].x); vmn.y = fminf(vmn.y, v[i].y);
                    }
                }
            }
        }
        if (deg == 0) {
            vmx = make_float2(0.f, 0.f);
            vmn = make_float2(0.f, 0.f);
        }
        short2v p;
        p.x = f2bf(vmx.x); p.y = f2bf(vmx.y);
        *(short2v*)(Abase + (wv * 4 + 1) * 272 + lane * 4) = p;
        p.x = f2bf(vmn.x); p.y = f2bf(vmn.y);
        *(short2v*)(Abase + (wv * 4 + 2) * 272 + lane * 4) = p;
        p.x = f2bf(vs.x); p.y = f2bf(vs.y);
        *(short2v*)(Abase + (wv * 4 + 3) * 272 + lane * 4) = p;
        if (lane == 0) cinv[wv] = 1.f / (float)max(deg, 1);
    }
    __syncthreads();   // A tile + cinv visible

    // ---- P1: MFMA GEMM qkv = A @ Wip^T  (M=16, N=384, K=128) ----
    const int quad = lane >> 4;
    const int col16 = lane & 15;

    f32x4 acc[6];
#pragma unroll
    for (int t = 0; t < 6; t++) acc[t] = (f32x4){0.f, 0.f, 0.f, 0.f};

    const char* Bg = (const char*)wipbf + (size_t)(wv * 96 + col16) * 64 + quad * 16;
#pragma unroll
    for (int ks = 0; ks < 4; ks++) {
        bf16x8 af = *(const bf16x8*)(Abase + col16 * 272 + ks * 64 + quad * 16);
#pragma unroll
        for (int t = 0; t < 6; t++) {
            bf16x8 bfr = *(const bf16x8*)(Bg + ks * 24576 + t * 1024);
            acc[t] = __builtin_amdgcn_mfma_f32_16x16x32_bf16(af, bfr, acc[t], 0, 0, 0);
        }
    }
    __syncthreads();   // all waves done reading A region

    // ---- P2: C-frags (+bias) -> qkv overlay rows node*5+s; mean row folded ----
    {
        const float ci = cinv[quad];   // node == quad
#pragma unroll
        for (int t = 0; t < 6; t++) {
            int col = wv * 96 + t * 16 + col16;
            float bias = bip[col];
#pragma unroll
            for (int reg = 0; reg < 4; reg++) {   // node=quad, s=reg
                R[(quad * 5 + reg) * QROW + col] = acc[t][reg] + bias;
            }
            R[(quad * 5 + 4) * QROW + col] = acc[t][3] * ci + bias;
        }
    }
    __syncthreads();

    // ---- P4: scores/softmax/PV, 2 heads per pass; PV -> global direct ----
#pragma unroll
    for (int hp = 0; hp < 2; hp++) {
        if (tid < 200) {
            int sub = (tid >= 100) ? 1 : 0;
            int rem = tid - sub * 100;
            int n = rem / 25, ij = rem - n * 25, i = ij / 5, j = ij - (ij / 5) * 5;
            int h = hp * 2 + sub;
            const float4* qr = (const float4*)&R[(n * 5 + i) * QROW + h * DH];
            const float4* kr = (const float4*)&R[(n * 5 + j) * QROW + C + h * DH];
            float s = 0.f;
#pragma unroll
            for (int d4 = 0; d4 < 8; d4++) {
                float4 q = qr[d4], k = kr[d4];
                s += q.x * k.x + q.y * k.y + q.z * k.z + q.w * k.w;
            }
            att[sub][n][i][j] = s * QK_SCALE;
        }
        __syncthreads();
        if (tid < 40) {
            int sub = (tid >= 20) ? 1 : 0;
            int rem = tid - sub * 20;
            int n = rem / 5, i = rem - (rem / 5) * 5;
            float m = att[sub][n][i][0];
#pragma unroll
            for (int j = 1; j < 5; j++) m = fmaxf(m, att[sub][n][i][j]);
            float e[5], l = 0.f;
#pragma unroll
            for (int j = 0; j < 5; j++) { e[j] = __expf(att[sub][n][i][j] - m); l += e[j]; }
            float inv = 0.2f / l;   // fold mean over 5 tokens
#pragma unroll
            for (int j = 0; j < 5; j++) att[sub][n][i][j] = e[j] * inv;
        }
        __syncthreads();
        {
            int sub = tid >> 7, rem = tid & 127, n = rem >> 5, d = rem & 31;
            int h = hp * 2 + sub;
            float a2 = 0.f;
#pragma unroll
            for (int j = 0; j < 5; j++) {
                float wj = att[sub][n][0][j] + att[sub][n][1][j] + att[sub][n][2][j]
                         + att[sub][n][3][j] + att[sub][n][4][j];
                a2 += wj * R[(n * 5 + j) * QROW + 2 * C + h * DH + d];
            }
            int node = node0 + n;
            if (node < n_nodes) omean_g[(size_t)node * C + h * DH + d] = a2;
        }
        __syncthreads();
    }
}

// ---------------------------------------------------------------------------
// K5: out = self(d_out) + omean @ Wop^T + bop. 64-row blocks, 8x4 tiles,
// strided col ownership (tn+32j), B row-major [128][36] per ks chunk.
// ---------------------------------------------------------------------------
__global__ __launch_bounds__(256, 3) void outproj_kernel(
    const float* __restrict__ omean_g, const float* __restrict__ Wop,
    const float* __restrict__ bop, float* __restrict__ out, int M)
{
    __shared__ float As[64 * 132];   // 33792 B
    __shared__ float Bs[128 * 36];   // 18432 B
    __shared__ float bopS[C];

    const int tid = threadIdx.x;
    const int m0 = blockIdx.x * 64;

    if (tid < C) bopS[tid] = bop[tid];

#pragma unroll
    for (int i = 0; i < 8; i++) {
        int id = tid + i * 256;
        int r = id >> 5, c4 = id & 31;
        float4 v = make_float4(0.f, 0.f, 0.f, 0.f);
        if (m0 + r < M) v = ((const float4*)omean_g)[(size_t)(m0 + r) * 32 + c4];
        *(float4*)&As[r * 132 + c4 * 4] = v;
    }

    const int tm = tid >> 5;   // 0..7
    const int tn = tid & 31;   // 0..31

    float acc[8][4];
#pragma unroll
    for (int m = 0; m < 8; m++)
#pragma unroll
        for (int j = 0; j < 4; j++) acc[m][j] = 0.f;

    for (int ks = 0; ks < 4; ks++) {
        __syncthreads();
#pragma unroll
        for (int i = 0; i < 4; i++) {
            int id = tid + i * 256;          // 1024 = 128 n x 8 q
            int n = id >> 3, q = id & 7;
            float4 w = ((const float4*)Wop)[(size_t)n * 32 + ks * 8 + q];
            *(float4*)&Bs[n * 36 + q * 4] = w;
        }
        __syncthreads();

        for (int k4 = 0; k4 < 8; k4++) {
            float4 a[8];
#pragma unroll
            for (int m = 0; m < 8; m++)
                a[m] = *(const float4*)&As[(tm * 8 + m) * 132 + ks * 32 + k4 * 4];
            float4 b[4];
#pragma unroll
            for (int j = 0; j < 4; j++)
                b[j] = *(const float4*)&Bs[(tn + 32 * j) * 36 + k4 * 4];
#pragma unroll
            for (int m = 0; m < 8; m++) {
                float4 av = a[m];
#pragma unroll
                for (int j = 0; j < 4; j++) {
                    float4 bv = b[j];
                    acc[m][j] += av.x * bv.x + av.y * bv.y
                               + av.z * bv.z + av.w * bv.w;
                }
            }
        }
    }

#pragma unroll
    for (int m = 0; m < 8; m++) {
        int row = m0 + tm * 8 + m;
        if (row < M) {
#pragma unroll
            for (int j = 0; j < 4; j++) {
                int col = tn + 32 * j;
                float* o = &out[(size_t)row * C + col];
                *o += acc[m][j] + bopS[col];
            }
        }
    }
}

// ---------------------------------------------------------------------------
extern "C" void kernel_launch(void* const* d_in, const int* in_sizes, int n_in,
                              void* d_out, int out_size, void* d_ws, size_t ws_size,
                              hipStream_t stream) {
    const float* x_user = (const float*)d_in[0];
    const float* x_item = (const float*)d_in[1];
    const int*   ei_u2i = (const int*)d_in[2];
    const int*   ei_i2u = (const int*)d_in[3];
    const float* W_nb   = (const float*)d_in[4];
    const float* b_nb   = (const float*)d_in[5];
    const float* W_self = (const float*)d_in[6];
    const float* b_self = (const float*)d_in[7];
    const float* Wip    = (const float*)d_in[8];
    const float* bip    = (const float*)d_in[9];
    const float* Wop    = (const float*)d_in[10];
    const float* bop    = (const float*)d_in[11];

    const int NU = in_sizes[0] / C;
    const int NI = in_sizes[1] / C;
    const int E1 = in_sizes[2] / 2;
    const int E2 = in_sizes[3] / 2;

    float* out_user = (float*)d_out;
    float* out_item = out_user + (size_t)NU * C;

    // workspace: wipbf (24576 floats) | h (rc) | omean (rc) | cur | csr
    float* ws = (float*)d_ws;
    short* wipbf     = (short*)ws;
    float* h_all     = ws + 24576;
    const size_t rc = (size_t)(NU + NI) * C;
    float* omean_all = h_all + rc;
    int*   cur       = (int*)(omean_all + rc);
    const int maxN   = (NU > NI) ? NU : NI;
    int*   csr       = cur + maxN;

    float* h_user = h_all;
    float* h_item = h_all + (size_t)NU * C;
    float* om_user = omean_all;
    float* om_item = omean_all + (size_t)NU * C;

    wip2bf_kernel<<<96, 256, 0, stream>>>(Wip, (unsigned*)wipbf);

    transform_kernel<<<(NU + 63) / 64, 256, 0, stream>>>(
        x_user, NU, W_nb, b_nb, W_self, b_self, h_user, out_user);
    transform_kernel<<<(NI + 63) / 64, 256, 0, stream>>>(
        x_item, NI, W_nb, b_nb, W_self, b_self, h_item, out_item);

    // direction A: user -> item
    zero_kernel<<<(NI + 255) / 256, 256, 0, stream>>>(cur, NI);
    hist_kernel<<<(E1 + 255) / 256, 256, 0, stream>>>(ei_u2i + E1, E1, cur);
    scan_kernel<<<1, 1024, 0, stream>>>(cur, NI);
    fill_kernel<<<(E1 + 255) / 256, 256, 0, stream>>>(ei_u2i, ei_u2i + E1, E1, cur, csr);
    attn_fused_kernel<<<(NI + ATN - 1) / ATN, 256, 0, stream>>>(
        h_user, csr, cur, out_item, wipbf, bip, om_item, NI);

    // direction B: item -> user
    zero_kernel<<<(NU + 255) / 256, 256, 0, stream>>>(cur, NU);
    hist_kernel<<<(E2 + 255) / 256, 256, 0, stream>>>(ei_i2u + E2, E2, cur);
    scan_kernel<<<1, 1024, 0, stream>>>(cur, NU);
    fill_kernel<<<(E2 + 255) / 256, 256, 0, stream>>>(ei_i2u, ei_i2u + E2, E2, cur, csr);
    attn_fused_kernel<<<(NU + ATN - 1) / ATN, 256, 0, stream>>>(
        h_item, csr, cur, out_user, wipbf, bip, om_user, NU);

    outproj_kernel<<<(NU + NI + 63) / 64, 256, 0, stream>>>(
        omean_all, Wop, bop, (float*)d_out, NU + NI);
}

// Round 3
// 785.922 us; speedup vs baseline: 1.4573x; 1.0431x over previous
//
#include <hip/hip_runtime.h>
#include <hip/hip_bf16.h>

// ---------------------------------------------------------------------------
// AttentionHeteroConv. R10 = R9 with:
//  (1) attn: per-head wave B-tiling (wave w computes head w's q,k,v cols) ->
//      whole attention runs in registers (shfl_xor butterfly over the 16-lane
//      node group). qkv LDS overlay deleted; ONE barrier per block; LDS 4.4KB
//      -> __launch_bounds__(256,6), ~6 blocks/CU.
//  (2) transform: both node types in one launch (row-ranged pointer select).
// CSR / outproj unchanged.
// ---------------------------------------------------------------------------

#define C 128
#define NHEAD 4
#define DH 32
#define QK_SCALE 0.17677669529663687f  // 1/sqrt(32)

typedef __attribute__((ext_vector_type(8))) short bf16x8;
typedef __attribute__((ext_vector_type(4))) short short4v;
typedef __attribute__((ext_vector_type(2))) short short2v;
typedef __attribute__((ext_vector_type(4))) float f32x4;

__device__ __forceinline__ short f2bf(float f) {
    unsigned u = __float_as_uint(f);
    unsigned r = u + 0x7FFFu + ((u >> 16) & 1u);   // round-to-nearest-even
    return (short)(r >> 16);
}

// ---------------------------------------------------------------------------
// K2: transform (merged): rows 0..NU-1 from x_user, NU..NTOT-1 from x_item.
// h = x@Wnb^T + bnb ; self = x@Wself^T + bself.  64 rows/block, 8x8 tiles,
// strided col ownership (tn+32j), B row-major [256][36] per ks chunk.
// ---------------------------------------------------------------------------
__global__ __launch_bounds__(256, 2) void transform_kernel(
    const float* __restrict__ xu, const float* __restrict__ xi,
    int NU, int NTOT,
    const float* __restrict__ Wnb, const float* __restrict__ bnb,
    const float* __restrict__ Wself, const float* __restrict__ bself,
    float* __restrict__ h, float* __restrict__ selfout)
{
    __shared__ float As[64 * 132];   // 33792 B
    __shared__ float Bs[256 * 36];   // 36864 B
    __shared__ float biasS[256];

    const int tid = threadIdx.x;
    const int row0 = blockIdx.x * 64;

    biasS[tid] = (tid < 128) ? bnb[tid] : bself[tid - 128];

#pragma unroll
    for (int i = 0; i < 8; i++) {
        int id = tid + i * 256;
        int r = id >> 5, c4 = id & 31;
        int row = row0 + r;
        float4 v = make_float4(0.f, 0.f, 0.f, 0.f);
        if (row < NTOT) {
            v = (row < NU) ? ((const float4*)xu)[(size_t)row * 32 + c4]
                           : ((const float4*)xi)[(size_t)(row - NU) * 32 + c4];
        }
        *(float4*)&As[r * 132 + c4 * 4] = v;
    }

    const int tm = tid >> 5;   // 0..7
    const int tn = tid & 31;   // 0..31

    float acc[8][8];
#pragma unroll
    for (int m = 0; m < 8; m++)
#pragma unroll
        for (int j = 0; j < 8; j++) acc[m][j] = 0.f;

    for (int ks = 0; ks < 4; ks++) {
        __syncthreads();
#pragma unroll
        for (int i = 0; i < 8; i++) {
            int id = tid + i * 256;          // 2048 = 256 n x 8 q
            int n = id >> 3, q = id & 7;
            const float4* src = (n < 128)
                ? &((const float4*)Wnb)[(size_t)n * 32 + ks * 8 + q]
                : &((const float4*)Wself)[(size_t)(n - 128) * 32 + ks * 8 + q];
            *(float4*)&Bs[n * 36 + q * 4] = *src;
        }
        __syncthreads();

        for (int k4 = 0; k4 < 8; k4++) {
            float4 a[8];
#pragma unroll
            for (int m = 0; m < 8; m++)
                a[m] = *(const float4*)&As[(tm * 8 + m) * 132 + ks * 32 + k4 * 4];
            float4 b[8];
#pragma unroll
            for (int j = 0; j < 8; j++)
                b[j] = *(const float4*)&Bs[(tn + 32 * j) * 36 + k4 * 4];
#pragma unroll
            for (int m = 0; m < 8; m++) {
                float4 av = a[m];
#pragma unroll
                for (int j = 0; j < 8; j++) {
                    float4 bv = b[j];
                    acc[m][j] += av.x * bv.x + av.y * bv.y
                               + av.z * bv.z + av.w * bv.w;
                }
            }
        }
    }

#pragma unroll
    for (int m = 0; m < 8; m++) {
        int row = row0 + tm * 8 + m;
        if (row < NTOT) {
#pragma unroll
            for (int j = 0; j < 8; j++) {
                int jj = tn + 32 * j;
                float v = acc[m][j] + biasS[jj];
                if (j < 4) h[(size_t)row * C + jj] = v;
                else       selfout[(size_t)row * C + (jj - 128)] = v;
            }
        }
    }
}

// ---------------------------------------------------------------------------
// CSR build: zero + histogram + exclusive-scan (single block) + fill.
// ---------------------------------------------------------------------------
__global__ __launch_bounds__(256) void zero_kernel(int* __restrict__ p, int n)
{
    int i = blockIdx.x * 256 + threadIdx.x;
    if (i < n) p[i] = 0;
}

__global__ __launch_bounds__(256) void hist_kernel(
    const int* __restrict__ dst, int n, int* __restrict__ cur)
{
    int i = blockIdx.x * 256 + threadIdx.x;
    if (i < n) atomicAdd(&cur[dst[i]], 1);
}

__global__ __launch_bounds__(1024) void scan_kernel(int* __restrict__ cur, int n)
{
    __shared__ int wsum[16];
    __shared__ int carryS;
    const int tid = threadIdx.x, lane = tid & 63, wv = tid >> 6;
    if (tid == 0) carryS = 0;
    __syncthreads();
    for (int base = 0; base < n; base += 1024) {
        int i = base + tid;
        int v = (i < n) ? cur[i] : 0;
        int x = v;
#pragma unroll
        for (int d = 1; d < 64; d <<= 1) {
            int t = __shfl_up(x, d, 64);
            if (lane >= d) x += t;
        }
        if (lane == 63) wsum[wv] = x;
        int carry = carryS;
        __syncthreads();
        int wpre = 0;
#pragma unroll
        for (int w2 = 0; w2 < 16; w2++) wpre += (w2 < wv) ? wsum[w2] : 0;
        int excl = x - v + wpre + carry;
        if (i < n) cur[i] = excl;
        __syncthreads();
        if (tid == 0) {
            int t = 0;
#pragma unroll
            for (int w2 = 0; w2 < 16; w2++) t += wsum[w2];
            carryS = carry + t;
        }
        __syncthreads();
    }
}

__global__ __launch_bounds__(256) void fill_kernel(
    const int* __restrict__ src, const int* __restrict__ dst, int n,
    int* __restrict__ cur, int* __restrict__ csr)
{
    int i = blockIdx.x * 256 + threadIdx.x;
    if (i < n) {
        int p = atomicAdd(&cur[dst[i]], 1);
        csr[p] = src[i];
    }
}

// ---------------------------------------------------------------------------
// K3b: Wip fp32 [384][128] -> bf16 MFMA image [ks][384][32] (dense, 98304 B).
// Element (ks,n,k) at byte ks*24576 + n*64 + k*2.
// ---------------------------------------------------------------------------
__global__ __launch_bounds__(256) void wip2bf_kernel(
    const float* __restrict__ Wip, unsigned* __restrict__ img)
{
    int id = blockIdx.x * 256 + threadIdx.x;     // 4*384*16 = 24576 pair-slots
    if (id >= 4 * 384 * 16) return;
    int ks = id / (384 * 16);
    int rem = id - ks * (384 * 16);
    int n = rem >> 4, kk = rem & 15;             // kk = pair index (2 bf16)
    float a = Wip[(size_t)n * C + ks * 32 + kk * 2 + 0];
    float b = Wip[(size_t)n * C + ks * 32 + kk * 2 + 1];
    unsigned pa = ((unsigned)(unsigned short)f2bf(a))
                | (((unsigned)(unsigned short)f2bf(b)) << 16);
    img[(size_t)ks * 6144 + n * 16 + kk] = pa;
}

// ---------------------------------------------------------------------------
// K4: fused gather-aggregate + bf16-MFMA qkv + IN-REGISTER attention.
// 4 nodes/block, 4 waves. Wave w computes head w's q,k,v columns:
// B N-tiles for wave w: {w*32, w*32+16, 128+w*32, 128+w*32+16, 256+w*32,
// 256+w*32+16}. C layout: quad = node, reg = token s, col = lane&15 (+16).
// Attention per 16-lane node group: 2 products/lane, shfl_xor butterfly
// (width 16), redundant softmax, PV from v accumulators. One barrier.
// ---------------------------------------------------------------------------
#define ATN 4

__global__ __launch_bounds__(256, 6) void attn_fused_kernel(
    const float* __restrict__ h_src, const int* __restrict__ csr,
    const int* __restrict__ cur, const float* __restrict__ selfF,
    const short* __restrict__ wipbf, const float* __restrict__ bip,
    float* __restrict__ omean_g, int n_nodes)
{
    __shared__ char Ash[16 * 272];   // bf16 A tile [16 rows][136 bf16]
    __shared__ float cinv[ATN];

    const int tid = threadIdx.x;
    const int lane = tid & 63;
    const int wv = tid >> 6;
    const int node0 = blockIdx.x * ATN;

    // ---- P0a: self rows (A row node*4+0, bf16) ----
    if (tid < 128) {
        int r = tid >> 5, c4 = tid & 31;
        int node = node0 + r;
        float4 v = make_float4(0.f, 0.f, 0.f, 0.f);
        if (node < n_nodes) v = ((const float4*)selfF)[(size_t)node * 32 + c4];
        short4v b;
        b.x = f2bf(v.x); b.y = f2bf(v.y); b.z = f2bf(v.z); b.w = f2bf(v.w);
        *(short4v*)(Ash + (r * 4) * 272 + c4 * 8) = b;
    }

    // ---- P0b: gather max/min/sum -> A rows wv*4+{1,2,3} (one node/wave) ----
    {
        const float2* h2 = (const float2*)h_src;
        int node = node0 + wv;
        float2 vs = make_float2(0.f, 0.f);
        float2 vmx = make_float2(-3.4e38f, -3.4e38f);
        float2 vmn = make_float2(3.4e38f, 3.4e38f);
        int deg = 0;
        if (node < n_nodes) {
            int start = (node == 0) ? 0 : cur[node - 1];
            int end = cur[node];
            deg = end - start;
            int e = start;
            for (; e + 8 <= end; e += 8) {
                float2 v[8];
#pragma unroll
                for (int i = 0; i < 8; i++) {
                    int s = csr[e + i];
                    v[i] = h2[(size_t)s * 64 + lane];
                }
#pragma unroll
                for (int i = 0; i < 8; i++) {
                    vs.x += v[i].x; vs.y += v[i].y;
                    vmx.x = fmaxf(vmx.x, v[i].x); vmx.y = fmaxf(vmx.y, v[i].y);
                    vmn.x = fminf(vmn.x, v[i].x); vmn.y = fminf(vmn.y, v[i].y);
                }
            }
            if (e < end) {   // masked full-width tail: one latency round
                int last = end - 1;
                float2 v[8];
#pragma unroll
                for (int i = 0; i < 8; i++) {
                    int idx = e + i;
                    int s = csr[(idx <= last) ? idx : last];
                    v[i] = h2[(size_t)s * 64 + lane];
                }
#pragma unroll
                for (int i = 0; i < 8; i++) {
                    if (e + i <= last) {   // wave-uniform
                        vs.x += v[i].x; vs.y += v[i].y;
                        vmx.x = fmaxf(vmx.x, v[i].x); vmx.y = fmaxf(vmx.y, v[i].y);
                        vmn.x = fminf(vmn.x, v[i].x); vmn.y = fminf(vmn.y, v[i].y);
                    }
                }
            }
        }
        if (deg == 0) {
            vmx = make_float2(0.f, 0.f);
            vmn = make_float2(0.f, 0.f);
        }
        short2v p;
        p.x = f2bf(vmx.x); p.y = f2bf(vmx.y);
        *(short2v*)(Ash + (wv * 4 + 1) * 272 + lane * 4) = p;
        p.x = f2bf(vmn.x); p.y = f2bf(vmn.y);
        *(short2v*)(Ash + (wv * 4 + 2) * 272 + lane * 4) = p;
        p.x = f2bf(vs.x); p.y = f2bf(vs.y);
        *(short2v*)(Ash + (wv * 4 + 3) * 272 + lane * 4) = p;
        if (lane == 0) cinv[wv] = 1.f / (float)max(deg, 1);
    }
    __syncthreads();   // the ONLY barrier

    // ---- P1: MFMA qkv for head wv only (M=16, N=6x16 tiles, K=128) ----
    const int quad = lane >> 4;      // node within block
    const int col16 = lane & 15;     // head-dim coordinate (cols c and c+16)

    f32x4 acc[6];
#pragma unroll
    for (int t = 0; t < 6; t++) acc[t] = (f32x4){0.f, 0.f, 0.f, 0.f};

#pragma unroll
    for (int ks = 0; ks < 4; ks++) {
        bf16x8 af = *(const bf16x8*)(Ash + col16 * 272 + ks * 64 + quad * 16);
#pragma unroll
        for (int t = 0; t < 6; t++) {
            int nb = wv * 32 + (t & 1) * 16 + (t >> 1) * 128 + col16;
            bf16x8 bfr = *(const bf16x8*)((const char*)wipbf
                          + (size_t)ks * 24576 + (size_t)nb * 64 + quad * 16);
            acc[t] = __builtin_amdgcn_mfma_f32_16x16x32_bf16(af, bfr, acc[t], 0, 0, 0);
        }
    }

    // ---- P2: in-register attention for head wv, node quad ----
    const float ci = cinv[quad];
    const float cis = ci * QK_SCALE;

    // biases for this wave's 6 columns
    const float bq0 = bip[wv * 32 + col16];
    const float bq1 = bip[wv * 32 + 16 + col16];
    const float bk0 = bip[128 + wv * 32 + col16];
    const float bk1 = bip[128 + wv * 32 + 16 + col16];
    const float bv0 = bip[256 + wv * 32 + col16];
    const float bv1 = bip[256 + wv * 32 + 16 + col16];
    const float bq0s = bq0 * QK_SCALE;
    const float bq1s = bq1 * QK_SCALE;

    // k tokens (5) at this lane's two columns
    float k0[5], k1[5];
#pragma unroll
    for (int s = 0; s < 4; s++) { k0[s] = acc[2][s] + bk0; k1[s] = acc[3][s] + bk1; }
    k0[4] = fmaf(acc[2][3], ci, bk0);
    k1[4] = fmaf(acc[3][3], ci, bk1);

    float wj[5] = {0.f, 0.f, 0.f, 0.f, 0.f};
#pragma unroll
    for (int i = 0; i < 5; i++) {
        float qi0 = (i < 4) ? fmaf(acc[0][i], QK_SCALE, bq0s)
                            : fmaf(acc[0][3], cis, bq0s);
        float qi1 = (i < 4) ? fmaf(acc[1][i], QK_SCALE, bq1s)
                            : fmaf(acc[1][3], cis, bq1s);
        float sv[5];
#pragma unroll
        for (int j = 0; j < 5; j++) sv[j] = qi0 * k0[j] + qi1 * k1[j];
        // butterfly allreduce over the 16-lane node group
#pragma unroll
        for (int j = 0; j < 5; j++) {
            sv[j] += __shfl_xor(sv[j], 1, 16);
            sv[j] += __shfl_xor(sv[j], 2, 16);
            sv[j] += __shfl_xor(sv[j], 4, 16);
            sv[j] += __shfl_xor(sv[j], 8, 16);
        }
        float m = sv[0];
#pragma unroll
        for (int j = 1; j < 5; j++) m = fmaxf(m, sv[j]);
        float e[5], l = 0.f;
#pragma unroll
        for (int j = 0; j < 5; j++) { e[j] = __expf(sv[j] - m); l += e[j]; }
        float inv = 0.2f / l;   // fold token-mean
#pragma unroll
        for (int j = 0; j < 5; j++) wj[j] = fmaf(e[j], inv, wj[j]);
    }

    // PV from v accumulators
    float o0 = 0.f, o1 = 0.f;
#pragma unroll
    for (int j = 0; j < 5; j++) {
        float v0 = (j < 4) ? (acc[4][j] + bv0) : fmaf(acc[4][3], ci, bv0);
        float v1 = (j < 4) ? (acc[5][j] + bv1) : fmaf(acc[5][3], ci, bv1);
        o0 = fmaf(wj[j], v0, o0);
        o1 = fmaf(wj[j], v1, o1);
    }

    int node = node0 + quad;
    if (node < n_nodes) {
        omean_g[(size_t)node * C + wv * 32 + col16] = o0;
        omean_g[(size_t)node * C + wv * 32 + 16 + col16] = o1;
    }
}

// ---------------------------------------------------------------------------
// K5: out = self(d_out) + omean @ Wop^T + bop. 64-row blocks, 8x4 tiles.
// ---------------------------------------------------------------------------
__global__ __launch_bounds__(256, 3) void outproj_kernel(
    const float* __restrict__ omean_g, const float* __restrict__ Wop,
    const float* __restrict__ bop, float* __restrict__ out, int M)
{
    __shared__ float As[64 * 132];   // 33792 B
    __shared__ float Bs[128 * 36];   // 18432 B
    __shared__ float bopS[C];

    const int tid = threadIdx.x;
    const int m0 = blockIdx.x * 64;

    if (tid < C) bopS[tid] = bop[tid];

#pragma unroll
    for (int i = 0; i < 8; i++) {
        int id = tid + i * 256;
        int r = id >> 5, c4 = id & 31;
        float4 v = make_float4(0.f, 0.f, 0.f, 0.f);
        if (m0 + r < M) v = ((const float4*)omean_g)[(size_t)(m0 + r) * 32 + c4];
        *(float4*)&As[r * 132 + c4 * 4] = v;
    }

    const int tm = tid >> 5;   // 0..7
    const int tn = tid & 31;   // 0..31

    float acc[8][4];
#pragma unroll
    for (int m = 0; m < 8; m++)
#pragma unroll
        for (int j = 0; j < 4; j++) acc[m][j] = 0.f;

    for (int ks = 0; ks < 4; ks++) {
        __syncthreads();
#pragma unroll
        for (int i = 0; i < 4; i++) {
            int id = tid + i * 256;          // 1024 = 128 n x 8 q
            int n = id >> 3, q = id & 7;
            float4 w = ((const float4*)Wop)[(size_t)n * 32 + ks * 8 + q];
            *(float4*)&Bs[n * 36 + q * 4] = w;
        }
        __syncthreads();

        for (int k4 = 0; k4 < 8; k4++) {
            float4 a[8];
#pragma unroll
            for (int m = 0; m < 8; m++)
                a[m] = *(const float4*)&As[(tm * 8 + m) * 132 + ks * 32 + k4 * 4];
            float4 b[4];
#pragma unroll
            for (int j = 0; j < 4; j++)
                b[j] = *(const float4*)&Bs[(tn + 32 * j) * 36 + k4 * 4];
#pragma unroll
            for (int m = 0; m < 8; m++) {
                float4 av = a[m];
#pragma unroll
                for (int j = 0; j < 4; j++) {
                    float4 bv = b[j];
                    acc[m][j] += av.x * bv.x + av.y * bv.y
                               + av.z * bv.z + av.w * bv.w;
                }
            }
        }
    }

#pragma unroll
    for (int m = 0; m < 8; m++) {
        int row = m0 + tm * 8 + m;
        if (row < M) {
#pragma unroll
            for (int j = 0; j < 4; j++) {
                int col = tn + 32 * j;
                float* o = &out[(size_t)row * C + col];
                *o += acc[m][j] + bopS[col];
            }
        }
    }
}

// ---------------------------------------------------------------------------
extern "C" void kernel_launch(void* const* d_in, const int* in_sizes, int n_in,
                              void* d_out, int out_size, void* d_ws, size_t ws_size,
                              hipStream_t stream) {
    const float* x_user = (const float*)d_in[0];
    const float* x_item = (const float*)d_in[1];
    const int*   ei_u2i = (const int*)d_in[2];
    const int*   ei_i2u = (const int*)d_in[3];
    const float* W_nb   = (const float*)d_in[4];
    const float* b_nb   = (const float*)d_in[5];
    const float* W_self = (const float*)d_in[6];
    const float* b_self = (const float*)d_in[7];
    const float* Wip    = (const float*)d_in[8];
    const float* bip    = (const float*)d_in[9];
    const float* Wop    = (const float*)d_in[10];
    const float* bop    = (const float*)d_in[11];

    const int NU = in_sizes[0] / C;
    const int NI = in_sizes[1] / C;
    const int E1 = in_sizes[2] / 2;
    const int E2 = in_sizes[3] / 2;
    const int NTOT = NU + NI;

    float* out_user = (float*)d_out;
    float* out_item = out_user + (size_t)NU * C;

    // workspace: wipbf (24576 floats) | h (rc) | omean (rc) | cur | csr
    float* ws = (float*)d_ws;
    short* wipbf     = (short*)ws;
    float* h_all     = ws + 24576;
    const size_t rc = (size_t)NTOT * C;
    float* omean_all = h_all + rc;
    int*   cur       = (int*)(omean_all + rc);
    const int maxN   = (NU > NI) ? NU : NI;
    int*   csr       = cur + maxN;

    float* h_user = h_all;
    float* h_item = h_all + (size_t)NU * C;
    float* om_user = omean_all;
    float* om_item = omean_all + (size_t)NU * C;

    wip2bf_kernel<<<96, 256, 0, stream>>>(Wip, (unsigned*)wipbf);

    transform_kernel<<<(NTOT + 63) / 64, 256, 0, stream>>>(
        x_user, x_item, NU, NTOT, W_nb, b_nb, W_self, b_self, h_all, (float*)d_out);

    // direction A: user -> item
    zero_kernel<<<(NI + 255) / 256, 256, 0, stream>>>(cur, NI);
    hist_kernel<<<(E1 + 255) / 256, 256, 0, stream>>>(ei_u2i + E1, E1, cur);
    scan_kernel<<<1, 1024, 0, stream>>>(cur, NI);
    fill_kernel<<<(E1 + 255) / 256, 256, 0, stream>>>(ei_u2i, ei_u2i + E1, E1, cur, csr);
    attn_fused_kernel<<<(NI + ATN - 1) / ATN, 256, 0, stream>>>(
        h_user, csr, cur, out_item, wipbf, bip, om_item, NI);

    // direction B: item -> user
    zero_kernel<<<(NU + 255) / 256, 256, 0, stream>>>(cur, NU);
    hist_kernel<<<(E2 + 255) / 256, 256, 0, stream>>>(ei_i2u + E2, E2, cur);
    scan_kernel<<<1, 1024, 0, stream>>>(cur, NU);
    fill_kernel<<<(E2 + 255) / 256, 256, 0, stream>>>(ei_i2u, ei_i2u + E2, E2, cur, csr);
    attn_fused_kernel<<<(NU + ATN - 1) / ATN, 256, 0, stream>>>(
        h_item, csr, cur, out_user, wipbf, bip, om_user, NU);

    outproj_kernel<<<(NTOT + 63) / 64, 256, 0, stream>>>(
        omean_all, Wop, bop, (float*)d_out, NTOT);
}

// Round 4
// 696.250 us; speedup vs baseline: 1.6450x; 1.1288x over previous
//
#include <hip/hip_runtime.h>
#include <hip/hip_bf16.h>

// ---------------------------------------------------------------------------
// AttentionHeteroConv. R11 = R10 with launch-count reduction (13 -> 9):
//  (1) prep kernel = wip2bf + zero(curA)+zero(curB) in one launch.
//  (2) merged hist over E1+E2 (one launch).
//  (3) scan: ONE launch, 2 blocks (one per direction), 4 elems/thread
//      (13 outer iterations instead of 49).
//  (4) order fillB->attnB->fillA->attnA: csr buffer reused; curB aliased
//      into om_item region (dead before attnA writes om_item) -> zero extra
//      workspace footprint.
//  (5) attn __launch_bounds__(256,8): 8 blocks/CU (VGPR 36 <= 64).
// attn/transform/outproj internals unchanged from R10.
// ---------------------------------------------------------------------------

#define C 128
#define NHEAD 4
#define DH 32
#define QK_SCALE 0.17677669529663687f  // 1/sqrt(32)

typedef __attribute__((ext_vector_type(8))) short bf16x8;
typedef __attribute__((ext_vector_type(4))) short short4v;
typedef __attribute__((ext_vector_type(2))) short short2v;
typedef __attribute__((ext_vector_type(4))) float f32x4;

__device__ __forceinline__ short f2bf(float f) {
    unsigned u = __float_as_uint(f);
    unsigned r = u + 0x7FFFu + ((u >> 16) & 1u);   // round-to-nearest-even
    return (short)(r >> 16);
}

// ---------------------------------------------------------------------------
// K2: transform (merged): rows 0..NU-1 from x_user, NU..NTOT-1 from x_item.
// h = x@Wnb^T + bnb ; self = x@Wself^T + bself.  64 rows/block, 8x8 tiles,
// strided col ownership (tn+32j), B row-major [256][36] per ks chunk.
// ---------------------------------------------------------------------------
__global__ __launch_bounds__(256, 2) void transform_kernel(
    const float* __restrict__ xu, const float* __restrict__ xi,
    int NU, int NTOT,
    const float* __restrict__ Wnb, const float* __restrict__ bnb,
    const float* __restrict__ Wself, const float* __restrict__ bself,
    float* __restrict__ h, float* __restrict__ selfout)
{
    __shared__ float As[64 * 132];   // 33792 B
    __shared__ float Bs[256 * 36];   // 36864 B
    __shared__ float biasS[256];

    const int tid = threadIdx.x;
    const int row0 = blockIdx.x * 64;

    biasS[tid] = (tid < 128) ? bnb[tid] : bself[tid - 128];

#pragma unroll
    for (int i = 0; i < 8; i++) {
        int id = tid + i * 256;
        int r = id >> 5, c4 = id & 31;
        int row = row0 + r;
        float4 v = make_float4(0.f, 0.f, 0.f, 0.f);
        if (row < NTOT) {
            v = (row < NU) ? ((const float4*)xu)[(size_t)row * 32 + c4]
                           : ((const float4*)xi)[(size_t)(row - NU) * 32 + c4];
        }
        *(float4*)&As[r * 132 + c4 * 4] = v;
    }

    const int tm = tid >> 5;   // 0..7
    const int tn = tid & 31;   // 0..31

    float acc[8][8];
#pragma unroll
    for (int m = 0; m < 8; m++)
#pragma unroll
        for (int j = 0; j < 8; j++) acc[m][j] = 0.f;

    for (int ks = 0; ks < 4; ks++) {
        __syncthreads();
#pragma unroll
        for (int i = 0; i < 8; i++) {
            int id = tid + i * 256;          // 2048 = 256 n x 8 q
            int n = id >> 3, q = id & 7;
            const float4* src = (n < 128)
                ? &((const float4*)Wnb)[(size_t)n * 32 + ks * 8 + q]
                : &((const float4*)Wself)[(size_t)(n - 128) * 32 + ks * 8 + q];
            *(float4*)&Bs[n * 36 + q * 4] = *src;
        }
        __syncthreads();

        for (int k4 = 0; k4 < 8; k4++) {
            float4 a[8];
#pragma unroll
            for (int m = 0; m < 8; m++)
                a[m] = *(const float4*)&As[(tm * 8 + m) * 132 + ks * 32 + k4 * 4];
            float4 b[8];
#pragma unroll
            for (int j = 0; j < 8; j++)
                b[j] = *(const float4*)&Bs[(tn + 32 * j) * 36 + k4 * 4];
#pragma unroll
            for (int m = 0; m < 8; m++) {
                float4 av = a[m];
#pragma unroll
                for (int j = 0; j < 8; j++) {
                    float4 bv = b[j];
                    acc[m][j] += av.x * bv.x + av.y * bv.y
                               + av.z * bv.z + av.w * bv.w;
                }
            }
        }
    }

#pragma unroll
    for (int m = 0; m < 8; m++) {
        int row = row0 + tm * 8 + m;
        if (row < NTOT) {
#pragma unroll
            for (int j = 0; j < 8; j++) {
                int jj = tn + 32 * j;
                float v = acc[m][j] + biasS[jj];
                if (j < 4) h[(size_t)row * C + jj] = v;
                else       selfout[(size_t)row * C + (jj - 128)] = v;
            }
        }
    }
}

// ---------------------------------------------------------------------------
// K1: prep = wip2bf (blocks 0..95) + zero curA (NI) + curB (NU).
// Wip fp32 [384][128] -> bf16 MFMA image [ks][384][32] (dense, 98304 B).
// ---------------------------------------------------------------------------
__global__ __launch_bounds__(256) void prep_kernel(
    const float* __restrict__ Wip, unsigned* __restrict__ img,
    int* __restrict__ curA, int nA, int* __restrict__ curB, int nB)
{
    const int tid = threadIdx.x;
    if (blockIdx.x < 96) {
        int id = blockIdx.x * 256 + tid;         // 4*384*16 = 24576 pair-slots
        int ks = id / (384 * 16);
        int rem = id - ks * (384 * 16);
        int n = rem >> 4, kk = rem & 15;         // kk = pair index (2 bf16)
        float a = Wip[(size_t)n * C + ks * 32 + kk * 2 + 0];
        float b = Wip[(size_t)n * C + ks * 32 + kk * 2 + 1];
        unsigned pa = ((unsigned)(unsigned short)f2bf(a))
                    | (((unsigned)(unsigned short)f2bf(b)) << 16);
        img[(size_t)ks * 6144 + n * 16 + kk] = pa;
    } else {
        int i = (blockIdx.x - 96) * 256 + tid;
        if (i < nA) curA[i] = 0;
        else if (i < nA + nB) curB[i - nA] = 0;
    }
}

// ---------------------------------------------------------------------------
// Merged histogram over both edge lists.
// ---------------------------------------------------------------------------
__global__ __launch_bounds__(256) void hist2_kernel(
    const int* __restrict__ dstA, int nA, int* __restrict__ curA,
    const int* __restrict__ dstB, int nB, int* __restrict__ curB)
{
    int i = blockIdx.x * 256 + threadIdx.x;
    if (i < nA) atomicAdd(&curA[dstA[i]], 1);
    else if (i < nA + nB) atomicAdd(&curB[dstB[i - nA]], 1);
}

// ---------------------------------------------------------------------------
// Scan: 2 blocks (block 0 -> curA/nA, block 1 -> curB/nB), 1024 threads,
// 4 elems/thread (4096/iteration).
// ---------------------------------------------------------------------------
__global__ __launch_bounds__(1024) void scan2_kernel(
    int* __restrict__ curA, int nA, int* __restrict__ curB, int nB)
{
    int* cur = (blockIdx.x == 0) ? curA : curB;
    const int n = (blockIdx.x == 0) ? nA : nB;

    __shared__ int wsum[16];
    __shared__ int carryS;
    const int tid = threadIdx.x, lane = tid & 63, wv = tid >> 6;
    if (tid == 0) carryS = 0;
    __syncthreads();
    for (int base = 0; base < n; base += 4096) {
        int i0 = base + tid * 4;
        int v0 = 0, v1 = 0, v2 = 0, v3 = 0;
        if (i0 + 3 < n) {
            int4 t = *(const int4*)&cur[i0];
            v0 = t.x; v1 = t.y; v2 = t.z; v3 = t.w;
        } else {
            if (i0 < n) v0 = cur[i0];
            if (i0 + 1 < n) v1 = cur[i0 + 1];
            if (i0 + 2 < n) v2 = cur[i0 + 2];
            if (i0 + 3 < n) v3 = cur[i0 + 3];
        }
        int s1 = v0 + v1, s2 = s1 + v2, s3 = s2 + v3;
        int x = s3;
#pragma unroll
        for (int d = 1; d < 64; d <<= 1) {
            int t = __shfl_up(x, d, 64);
            if (lane >= d) x += t;
        }
        if (lane == 63) wsum[wv] = x;
        int carry = carryS;
        __syncthreads();
        int wpre = 0;
#pragma unroll
        for (int w2 = 0; w2 < 16; w2++) wpre += (w2 < wv) ? wsum[w2] : 0;
        int excl = x - s3 + wpre + carry;
        if (i0 + 3 < n) {
            int4 st; st.x = excl; st.y = excl + v0; st.z = excl + s1; st.w = excl + s2;
            *(int4*)&cur[i0] = st;
        } else {
            if (i0 < n) cur[i0] = excl;
            if (i0 + 1 < n) cur[i0 + 1] = excl + v0;
            if (i0 + 2 < n) cur[i0 + 2] = excl + s1;
            if (i0 + 3 < n) cur[i0 + 3] = excl + s2;
        }
        __syncthreads();
        if (tid == 0) {
            int t = 0;
#pragma unroll
            for (int w2 = 0; w2 < 16; w2++) t += wsum[w2];
            carryS = carry + t;
        }
        __syncthreads();
    }
}

__global__ __launch_bounds__(256) void fill_kernel(
    const int* __restrict__ src, const int* __restrict__ dst, int n,
    int* __restrict__ cur, int* __restrict__ csr)
{
    int i = blockIdx.x * 256 + threadIdx.x;
    if (i < n) {
        int p = atomicAdd(&cur[dst[i]], 1);
        csr[p] = src[i];
    }
}

// ---------------------------------------------------------------------------
// K4: fused gather-aggregate + bf16-MFMA qkv + IN-REGISTER attention.
// 4 nodes/block, 4 waves. Wave w computes head w's q,k,v columns.
// 8 blocks/CU (VGPR 36 <= 64, LDS 4.6KB).
// ---------------------------------------------------------------------------
#define ATN 4

__global__ __launch_bounds__(256, 8) void attn_fused_kernel(
    const float* __restrict__ h_src, const int* __restrict__ csr,
    const int* __restrict__ cur, const float* __restrict__ selfF,
    const short* __restrict__ wipbf, const float* __restrict__ bip,
    float* __restrict__ omean_g, int n_nodes)
{
    __shared__ char Ash[16 * 272];   // bf16 A tile [16 rows][136 bf16]
    __shared__ float cinv[ATN];

    const int tid = threadIdx.x;
    const int lane = tid & 63;
    const int wv = tid >> 6;
    const int node0 = blockIdx.x * ATN;

    // ---- P0a: self rows (A row node*4+0, bf16) ----
    if (tid < 128) {
        int r = tid >> 5, c4 = tid & 31;
        int node = node0 + r;
        float4 v = make_float4(0.f, 0.f, 0.f, 0.f);
        if (node < n_nodes) v = ((const float4*)selfF)[(size_t)node * 32 + c4];
        short4v b;
        b.x = f2bf(v.x); b.y = f2bf(v.y); b.z = f2bf(v.z); b.w = f2bf(v.w);
        *(short4v*)(Ash + (r * 4) * 272 + c4 * 8) = b;
    }

    // ---- P0b: gather max/min/sum -> A rows wv*4+{1,2,3} (one node/wave) ----
    {
        const float2* h2 = (const float2*)h_src;
        int node = node0 + wv;
        float2 vs = make_float2(0.f, 0.f);
        float2 vmx = make_float2(-3.4e38f, -3.4e38f);
        float2 vmn = make_float2(3.4e38f, 3.4e38f);
        int deg = 0;
        if (node < n_nodes) {
            int start = (node == 0) ? 0 : cur[node - 1];
            int end = cur[node];
            deg = end - start;
            int e = start;
            for (; e + 8 <= end; e += 8) {
                float2 v[8];
#pragma unroll
                for (int i = 0; i < 8; i++) {
                    int s = csr[e + i];
                    v[i] = h2[(size_t)s * 64 + lane];
                }
#pragma unroll
                for (int i = 0; i < 8; i++) {
                    vs.x += v[i].x; vs.y += v[i].y;
                    vmx.x = fmaxf(vmx.x, v[i].x); vmx.y = fmaxf(vmx.y, v[i].y);
                    vmn.x = fminf(vmn.x, v[i].x); vmn.y = fminf(vmn.y, v[i].y);
                }
            }
            if (e < end) {   // masked full-width tail: one latency round
                int last = end - 1;
                float2 v[8];
#pragma unroll
                for (int i = 0; i < 8; i++) {
                    int idx = e + i;
                    int s = csr[(idx <= last) ? idx : last];
                    v[i] = h2[(size_t)s * 64 + lane];
                }
#pragma unroll
                for (int i = 0; i < 8; i++) {
                    if (e + i <= last) {   // wave-uniform
                        vs.x += v[i].x; vs.y += v[i].y;
                        vmx.x = fmaxf(vmx.x, v[i].x); vmx.y = fmaxf(vmx.y, v[i].y);
                        vmn.x = fminf(vmn.x, v[i].x); vmn.y = fminf(vmn.y, v[i].y);
                    }
                }
            }
        }
        if (deg == 0) {
            vmx = make_float2(0.f, 0.f);
            vmn = make_float2(0.f, 0.f);
        }
        short2v p;
        p.x = f2bf(vmx.x); p.y = f2bf(vmx.y);
        *(short2v*)(Ash + (wv * 4 + 1) * 272 + lane * 4) = p;
        p.x = f2bf(vmn.x); p.y = f2bf(vmn.y);
        *(short2v*)(Ash + (wv * 4 + 2) * 272 + lane * 4) = p;
        p.x = f2bf(vs.x); p.y = f2bf(vs.y);
        *(short2v*)(Ash + (wv * 4 + 3) * 272 + lane * 4) = p;
        if (lane == 0) cinv[wv] = 1.f / (float)max(deg, 1);
    }
    __syncthreads();   // the ONLY barrier

    // ---- P1: MFMA qkv for head wv only (M=16, N=6x16 tiles, K=128) ----
    const int quad = lane >> 4;      // node within block
    const int col16 = lane & 15;     // head-dim coordinate (cols c and c+16)

    f32x4 acc[6];
#pragma unroll
    for (int t = 0; t < 6; t++) acc[t] = (f32x4){0.f, 0.f, 0.f, 0.f};

#pragma unroll
    for (int ks = 0; ks < 4; ks++) {
        bf16x8 af = *(const bf16x8*)(Ash + col16 * 272 + ks * 64 + quad * 16);
#pragma unroll
        for (int t = 0; t < 6; t++) {
            int nb = wv * 32 + (t & 1) * 16 + (t >> 1) * 128 + col16;
            bf16x8 bfr = *(const bf16x8*)((const char*)wipbf
                          + (size_t)ks * 24576 + (size_t)nb * 64 + quad * 16);
            acc[t] = __builtin_amdgcn_mfma_f32_16x16x32_bf16(af, bfr, acc[t], 0, 0, 0);
        }
    }

    // ---- P2: in-register attention for head wv, node quad ----
    const float ci = cinv[quad];
    const float cis = ci * QK_SCALE;

    const float bq0 = bip[wv * 32 + col16];
    const float bq1 = bip[wv * 32 + 16 + col16];
    const float bk0 = bip[128 + wv * 32 + col16];
    const float bk1 = bip[128 + wv * 32 + 16 + col16];
    const float bv0 = bip[256 + wv * 32 + col16];
    const float bv1 = bip[256 + wv * 32 + 16 + col16];
    const float bq0s = bq0 * QK_SCALE;
    const float bq1s = bq1 * QK_SCALE;

    float k0[5], k1[5];
#pragma unroll
    for (int s = 0; s < 4; s++) { k0[s] = acc[2][s] + bk0; k1[s] = acc[3][s] + bk1; }
    k0[4] = fmaf(acc[2][3], ci, bk0);
    k1[4] = fmaf(acc[3][3], ci, bk1);

    float wj[5] = {0.f, 0.f, 0.f, 0.f, 0.f};
#pragma unroll
    for (int i = 0; i < 5; i++) {
        float qi0 = (i < 4) ? fmaf(acc[0][i], QK_SCALE, bq0s)
                            : fmaf(acc[0][3], cis, bq0s);
        float qi1 = (i < 4) ? fmaf(acc[1][i], QK_SCALE, bq1s)
                            : fmaf(acc[1][3], cis, bq1s);
        float sv[5];
#pragma unroll
        for (int j = 0; j < 5; j++) sv[j] = qi0 * k0[j] + qi1 * k1[j];
#pragma unroll
        for (int j = 0; j < 5; j++) {
            sv[j] += __shfl_xor(sv[j], 1, 16);
            sv[j] += __shfl_xor(sv[j], 2, 16);
            sv[j] += __shfl_xor(sv[j], 4, 16);
            sv[j] += __shfl_xor(sv[j], 8, 16);
        }
        float m = sv[0];
#pragma unroll
        for (int j = 1; j < 5; j++) m = fmaxf(m, sv[j]);
        float e[5], l = 0.f;
#pragma unroll
        for (int j = 0; j < 5; j++) { e[j] = __expf(sv[j] - m); l += e[j]; }
        float inv = 0.2f / l;   // fold token-mean
#pragma unroll
        for (int j = 0; j < 5; j++) wj[j] = fmaf(e[j], inv, wj[j]);
    }

    float o0 = 0.f, o1 = 0.f;
#pragma unroll
    for (int j = 0; j < 5; j++) {
        float v0 = (j < 4) ? (acc[4][j] + bv0) : fmaf(acc[4][3], ci, bv0);
        float v1 = (j < 4) ? (acc[5][j] + bv1) : fmaf(acc[5][3], ci, bv1);
        o0 = fmaf(wj[j], v0, o0);
        o1 = fmaf(wj[j], v1, o1);
    }

    int node = node0 + quad;
    if (node < n_nodes) {
        omean_g[(size_t)node * C + wv * 32 + col16] = o0;
        omean_g[(size_t)node * C + wv * 32 + 16 + col16] = o1;
    }
}

// ---------------------------------------------------------------------------
// K5: out = self(d_out) + omean @ Wop^T + bop. 64-row blocks, 8x4 tiles.
// ---------------------------------------------------------------------------
__global__ __launch_bounds__(256, 3) void outproj_kernel(
    const float* __restrict__ omean_g, const float* __restrict__ Wop,
    const float* __restrict__ bop, float* __restrict__ out, int M)
{
    __shared__ float As[64 * 132];   // 33792 B
    __shared__ float Bs[128 * 36];   // 18432 B
    __shared__ float bopS[C];

    const int tid = threadIdx.x;
    const int m0 = blockIdx.x * 64;

    if (tid < C) bopS[tid] = bop[tid];

#pragma unroll
    for (int i = 0; i < 8; i++) {
        int id = tid + i * 256;
        int r = id >> 5, c4 = id & 31;
        float4 v = make_float4(0.f, 0.f, 0.f, 0.f);
        if (m0 + r < M) v = ((const float4*)omean_g)[(size_t)(m0 + r) * 32 + c4];
        *(float4*)&As[r * 132 + c4 * 4] = v;
    }

    const int tm = tid >> 5;   // 0..7
    const int tn = tid & 31;   // 0..31

    float acc[8][4];
#pragma unroll
    for (int m = 0; m < 8; m++)
#pragma unroll
        for (int j = 0; j < 4; j++) acc[m][j] = 0.f;

    for (int ks = 0; ks < 4; ks++) {
        __syncthreads();
#pragma unroll
        for (int i = 0; i < 4; i++) {
            int id = tid + i * 256;          // 1024 = 128 n x 8 q
            int n = id >> 3, q = id & 7;
            float4 w = ((const float4*)Wop)[(size_t)n * 32 + ks * 8 + q];
            *(float4*)&Bs[n * 36 + q * 4] = w;
        }
        __syncthreads();

        for (int k4 = 0; k4 < 8; k4++) {
            float4 a[8];
#pragma unroll
            for (int m = 0; m < 8; m++)
                a[m] = *(const float4*)&As[(tm * 8 + m) * 132 + ks * 32 + k4 * 4];
            float4 b[4];
#pragma unroll
            for (int j = 0; j < 4; j++)
                b[j] = *(const float4*)&Bs[(tn + 32 * j) * 36 + k4 * 4];
#pragma unroll
            for (int m = 0; m < 8; m++) {
                float4 av = a[m];
#pragma unroll
                for (int j = 0; j < 4; j++) {
                    float4 bv = b[j];
                    acc[m][j] += av.x * bv.x + av.y * bv.y
                               + av.z * bv.z + av.w * bv.w;
                }
            }
        }
    }

#pragma unroll
    for (int m = 0; m < 8; m++) {
        int row = m0 + tm * 8 + m;
        if (row < M) {
#pragma unroll
            for (int j = 0; j < 4; j++) {
                int col = tn + 32 * j;
                float* o = &out[(size_t)row * C + col];
                *o += acc[m][j] + bopS[col];
            }
        }
    }
}

// ---------------------------------------------------------------------------
extern "C" void kernel_launch(void* const* d_in, const int* in_sizes, int n_in,
                              void* d_out, int out_size, void* d_ws, size_t ws_size,
                              hipStream_t stream) {
    const float* x_user = (const float*)d_in[0];
    const float* x_item = (const float*)d_in[1];
    const int*   ei_u2i = (const int*)d_in[2];
    const int*   ei_i2u = (const int*)d_in[3];
    const float* W_nb   = (const float*)d_in[4];
    const float* b_nb   = (const float*)d_in[5];
    const float* W_self = (const float*)d_in[6];
    const float* b_self = (const float*)d_in[7];
    const float* Wip    = (const float*)d_in[8];
    const float* bip    = (const float*)d_in[9];
    const float* Wop    = (const float*)d_in[10];
    const float* bop    = (const float*)d_in[11];

    const int NU = in_sizes[0] / C;
    const int NI = in_sizes[1] / C;
    const int E1 = in_sizes[2] / 2;
    const int E2 = in_sizes[3] / 2;
    const int NTOT = NU + NI;

    float* out_user = (float*)d_out;
    float* out_item = out_user + (size_t)NU * C;

    // workspace: wipbf (24576 floats) | h (rc) | omean (rc) | curA (maxN) | csr
    // curB is ALIASED into the om_item region (dead before attnA writes it).
    float* ws = (float*)d_ws;
    short* wipbf     = (short*)ws;
    float* h_all     = ws + 24576;
    const size_t rc = (size_t)NTOT * C;
    float* omean_all = h_all + rc;
    int*   curA      = (int*)(omean_all + rc);     // item-degree CSR ptrs (NI)
    const int maxN   = (NU > NI) ? NU : NI;
    int*   csr       = curA + maxN;

    float* h_user = h_all;
    float* h_item = h_all + (size_t)NU * C;
    float* om_user = omean_all;
    float* om_item = omean_all + (size_t)NU * C;
    int*   curB    = (int*)om_item;                // user-degree CSR ptrs (NU)

    // K1: wip2bf + zero both cur arrays
    prep_kernel<<<96 + (NTOT + 255) / 256, 256, 0, stream>>>(
        Wip, (unsigned*)wipbf, curA, NI, curB, NU);

    // K2: transform (both node types)
    transform_kernel<<<(NTOT + 63) / 64, 256, 0, stream>>>(
        x_user, x_item, NU, NTOT, W_nb, b_nb, W_self, b_self, h_all, (float*)d_out);

    // K3: merged histogram (dir A dsts = items, dir B dsts = users)
    hist2_kernel<<<(E1 + E2 + 255) / 256, 256, 0, stream>>>(
        ei_u2i + E1, E1, curA, ei_i2u + E2, E2, curB);

    // K4: both scans in one launch (2 blocks)
    scan2_kernel<<<2, 1024, 0, stream>>>(curA, NI, curB, NU);

    // direction B first (csr buffer reused; curB@om_item dies before attnA)
    fill_kernel<<<(E2 + 255) / 256, 256, 0, stream>>>(ei_i2u, ei_i2u + E2, E2, curB, csr);
    attn_fused_kernel<<<(NU + ATN - 1) / ATN, 256, 0, stream>>>(
        h_item, csr, curB, out_user, wipbf, bip, om_user, NU);

    // direction A
    fill_kernel<<<(E1 + 255) / 256, 256, 0, stream>>>(ei_u2i, ei_u2i + E1, E1, curA, csr);
    attn_fused_kernel<<<(NI + ATN - 1) / ATN, 256, 0, stream>>>(
        h_user, csr, curA, out_item, wipbf, bip, om_item, NI);

    outproj_kernel<<<(NTOT + 63) / 64, 256, 0, stream>>>(
        omean_all, Wop, bop, (float*)d_out, NTOT);
}